// Round 13
// baseline (477.370 us; speedup 1.0000x reference)
//
#include <hip/hip_runtime.h>
#include <stdint.h>

#define BATCH 4096
#define NJ 18
#define DIMM 512
#define HEADS 8
#define DEPTH 64
#define MROWS (BATCH*NJ)               // 73728
#define ATT_OFF ((size_t)MROWS*DIMM)   // start of att in d_out (floats)

typedef float f32x4 __attribute__((ext_vector_type(4)));
typedef _Float16 f16_t;
typedef _Float16 f16x8 __attribute__((ext_vector_type(8)));

// global -> LDS direct copy, 16 B per lane. LDS dest is wave-uniform base
// + lane*16 (linear); global src is per-lane.
__device__ __forceinline__ void gl_lds16(const unsigned int* g, unsigned int* l) {
    __builtin_amdgcn_global_load_lds(g, l, 16, 0, 0);
}

// ---------------------------------------------------------------------------
// Kernel 0: W[k][n] (f32) -> tiled+swizzled f16 image T.
// Tile (nb, ks) = rows nb*128..+127, k ks*64..+63, one contiguous 16 KB chunk:
//   f16x8 group gk of row rr at vec (nb*8+ks)*1024 + rr*8 + (gk ^ (rr&7))
// ---------------------------------------------------------------------------
__global__ __launch_bounds__(256) void convert_w_kernel(
    const float* __restrict__ W0, const float* __restrict__ W1,
    const float* __restrict__ W2, const float* __restrict__ W3,
    f16_t* __restrict__ T0, f16_t* __restrict__ T1,
    f16_t* __restrict__ T2, f16_t* __restrict__ T3)
{
    const float* W = blockIdx.z == 0 ? W0 : blockIdx.z == 1 ? W1 : blockIdx.z == 2 ? W2 : W3;
    f16_t* T       = blockIdx.z == 0 ? T0 : blockIdx.z == 1 ? T1 : blockIdx.z == 2 ? T2 : T3;
    __shared__ float ld[64][65];
    int k0 = blockIdx.y * 64, n0 = blockIdx.x * 64;
    int tid = threadIdx.x;
    #pragma unroll
    for (int it = 0; it < 16; ++it) {
        int idx = tid + it * 256;
        int kk = idx >> 6, nn = idx & 63;
        ld[kk][nn] = W[(size_t)(k0 + kk) * DIMM + n0 + nn];
    }
    __syncthreads();
    f16x8* T8 = (f16x8*)T;
    #pragma unroll
    for (int it = 0; it < 2; ++it) {
        int c = tid + it * 256;            // 512 f16x8 chunks per 64x64 tile
        int nn = c >> 3, c8 = c & 7;
        int n = n0 + nn, k = k0 + c8 * 8;
        f16x8 val;
        #pragma unroll
        for (int e = 0; e < 8; ++e) val[e] = (f16_t)ld[c8 * 8 + e][nn];
        size_t vi = (size_t)((n >> 7) * 8 + (k >> 6)) * 1024
                  + (n & 127) * 8 + (((k >> 3) & 7) ^ (n & 7));
        T8[vi] = val;
    }
}

// ---------------------------------------------------------------------------
// qkv GEMM: C = A @ W. 256x256 tile, BK=64, 512 thr = 8 waves (2x4), per-wave
// 128x64 output via 8x4x2 of mfma_f32_16x16x32_f16 (64 MFMA/wave/k-step).
// A f32 reg-staged + cvt into XOR-swizzled As (32 KB); B = two pre-swizzled
// 16 KB images via gl_lds (32 KB). LDS 64 KB -> 2 blocks/CU.
// XCD-aware bijective block swizzle (576 blocks/slice, %8==0).
// ---------------------------------------------------------------------------
__global__ __launch_bounds__(512) void gemm_qkv_kernel(
    const float* __restrict__ A0, const float* __restrict__ A1,
    const float* __restrict__ A2,
    const f16_t* __restrict__ B0, const f16_t* __restrict__ B1,
    const f16_t* __restrict__ B2,
    f16_t* __restrict__ C0, f16_t* __restrict__ C1, f16_t* __restrict__ C2)
{
    const float* A  = blockIdx.z == 0 ? A0 : blockIdx.z == 1 ? A1 : A2;
    const f16_t* Bt = blockIdx.z == 0 ? B0 : blockIdx.z == 1 ? B1 : B2;
    f16_t* C        = blockIdx.z == 0 ? C0 : blockIdx.z == 1 ? C1 : C2;

    const int p = blockIdx.x + 2 * blockIdx.y;            // nwg = 576
    const int logical = (p & 7) * (576 / 8) + (p >> 3);
    const int bn = (logical & 1) * 256;
    const int bm = (logical >> 1) * 256;

    __shared__ __align__(16) f16_t As[256 * 64];          // 32 KB, XOR-swizzled
    __shared__ __align__(16) f16_t Bs[2 * 128 * 64];      // 32 KB, 2 images

    const int tid = threadIdx.x;
    const int lane = tid & 63;
    const int wv = tid >> 6;                              // 0..7
    const int wm = wv >> 2, wn = wv & 3;                  // 2 x 4 wave grid
    const int l15 = lane & 15, lg = lane >> 4;
    const int swz = (l15 & 7) << 4;                       // byte XOR for reads
    const int koffb[2] = { (lg * 16) ^ swz, (lg * 16 + 64) ^ swz };

    f32x4 acc[8][4] = {};

    for (int ks = 0; ks < 8; ++ks) {
        __syncthreads();
        {   // B: two 16 KB tiles (bn>>7, +1) via gl_lds, 32 chunks of 1 KB
            const unsigned int* bt0 =
                (const unsigned int*)(Bt + (size_t)(((bn >> 7) + 0) * 8 + ks) * 8192);
            const unsigned int* bt1 =
                (const unsigned int*)(Bt + (size_t)(((bn >> 7) + 1) * 8 + ks) * 8192);
            unsigned int* bs = (unsigned int*)Bs;
            #pragma unroll
            for (int it = 0; it < 4; ++it) {
                int chunk = wv * 4 + it;                  // 0..31, wave-uniform
                const unsigned int* src =
                    (chunk < 16 ? bt0 : bt1) + (chunk & 15) * 256 + lane * 4;
                gl_lds16(src, bs + chunk * 256);
            }
        }
        {   // A: 256x64 f32 reg-stage + cvt; swizzled ds_write (2048 chunks)
            #pragma unroll
            for (int r = 0; r < 4; ++r) {
                int c = tid + r * 512;
                int row = c >> 3, kc = c & 7;
                const f32x4* p4 = (const f32x4*)(A + (size_t)(bm + row) * DIMM + ks * 64 + kc * 8);
                f32x4 a0 = p4[0], a1 = p4[1];
                f16x8 val;
                val[0] = (f16_t)a0[0]; val[1] = (f16_t)a0[1];
                val[2] = (f16_t)a0[2]; val[3] = (f16_t)a0[3];
                val[4] = (f16_t)a1[0]; val[5] = (f16_t)a1[1];
                val[6] = (f16_t)a1[2]; val[7] = (f16_t)a1[3];
                ((f16x8*)As)[row * 8 + (kc ^ (row & 7))] = val;
            }
        }
        __syncthreads();

        #pragma unroll
        for (int kk = 0; kk < 2; ++kk) {
            const int koff = koffb[kk];
            f16x8 af[8], bfr[4];
            #pragma unroll
            for (int mi = 0; mi < 8; ++mi) {
                int row = wm * 128 + mi * 16 + l15;       // 0..255
                af[mi] = *(const f16x8*)((const char*)As + row * 128 + koff);
            }
            #pragma unroll
            for (int ni = 0; ni < 4; ++ni) {
                int rn = wn * 64 + ni * 16 + l15;         // 0..255
                bfr[ni] = *(const f16x8*)((const char*)Bs
                            + (rn >> 7) * 16384 + (rn & 127) * 128 + koff);
            }
            #pragma unroll
            for (int mi = 0; mi < 8; ++mi)
                #pragma unroll
                for (int ni = 0; ni < 4; ++ni)
                    acc[mi][ni] = __builtin_amdgcn_mfma_f32_16x16x32_f16(
                        af[mi], bfr[ni], acc[mi][ni], 0, 0, 0);
        }
    }

    // epilogue: C/D layout col = lane&15, row = (lane>>4)*4 + reg  [HW-verified]
    #pragma unroll
    for (int mi = 0; mi < 8; ++mi) {
        #pragma unroll
        for (int ni = 0; ni < 4; ++ni) {
            int col = bn + wn * 64 + ni * 16 + l15;
            int rowb = bm + wm * 128 + mi * 16 + lg * 4;
            f32x4 v = acc[mi][ni];
            #pragma unroll
            for (int r = 0; r < 4; ++r)
                C[(size_t)(rowb + r) * DIMM + col] = (f16_t)v[r];
        }
    }
}

// ---------------------------------------------------------------------------
// Final GEMM: out = ao @ Wo + bo. 256x256 tile, 512 thr, BOTH operands via
// gl_lds from pre-tiled/pre-swizzled 128-row-tile images (two each). 64 KB LDS.
// ---------------------------------------------------------------------------
__global__ __launch_bounds__(512) void gemm_out_kernel(
    const f16_t* __restrict__ Aimg, const f16_t* __restrict__ Bt,
    float* __restrict__ C, const float* __restrict__ bias)
{
    const int p = blockIdx.x + 2 * blockIdx.y;            // nwg = 576
    const int logical = (p & 7) * (576 / 8) + (p >> 3);
    const int bn = (logical & 1) * 256;
    const int bm = (logical >> 1) * 256;

    __shared__ __align__(16) f16_t As[2 * 128 * 64];      // 32 KB
    __shared__ __align__(16) f16_t Bs[2 * 128 * 64];      // 32 KB

    const int tid = threadIdx.x;
    const int lane = tid & 63;
    const int wv = tid >> 6;
    const int wm = wv >> 2, wn = wv & 3;
    const int l15 = lane & 15, lg = lane >> 4;
    const int swz = (l15 & 7) << 4;
    const int koffb[2] = { (lg * 16) ^ swz, (lg * 16 + 64) ^ swz };

    f32x4 acc[8][4] = {};

    for (int ks = 0; ks < 8; ++ks) {
        __syncthreads();
        {   // B: two tiles, 32 chunks
            const unsigned int* bt0 =
                (const unsigned int*)(Bt + (size_t)(((bn >> 7) + 0) * 8 + ks) * 8192);
            const unsigned int* bt1 =
                (const unsigned int*)(Bt + (size_t)(((bn >> 7) + 1) * 8 + ks) * 8192);
            unsigned int* bs = (unsigned int*)Bs;
            #pragma unroll
            for (int it = 0; it < 4; ++it) {
                int chunk = wv * 4 + it;
                const unsigned int* src =
                    (chunk < 16 ? bt0 : bt1) + (chunk & 15) * 256 + lane * 4;
                gl_lds16(src, bs + chunk * 256);
            }
        }
        {   // A: two tiles, 32 chunks
            const unsigned int* at0 =
                (const unsigned int*)(Aimg + (size_t)(((bm >> 7) + 0) * 8 + ks) * 8192);
            const unsigned int* at1 =
                (const unsigned int*)(Aimg + (size_t)(((bm >> 7) + 1) * 8 + ks) * 8192);
            unsigned int* as = (unsigned int*)As;
            #pragma unroll
            for (int it = 0; it < 4; ++it) {
                int chunk = wv * 4 + it;
                const unsigned int* src =
                    (chunk < 16 ? at0 : at1) + (chunk & 15) * 256 + lane * 4;
                gl_lds16(src, as + chunk * 256);
            }
        }
        __syncthreads();

        #pragma unroll
        for (int kk = 0; kk < 2; ++kk) {
            const int koff = koffb[kk];
            f16x8 af[8], bfr[4];
            #pragma unroll
            for (int mi = 0; mi < 8; ++mi) {
                int row = wm * 128 + mi * 16 + l15;       // 0..255
                af[mi] = *(const f16x8*)((const char*)As
                            + (row >> 7) * 16384 + (row & 127) * 128 + koff);
            }
            #pragma unroll
            for (int ni = 0; ni < 4; ++ni) {
                int rn = wn * 64 + ni * 16 + l15;
                bfr[ni] = *(const f16x8*)((const char*)Bs
                            + (rn >> 7) * 16384 + (rn & 127) * 128 + koff);
            }
            #pragma unroll
            for (int mi = 0; mi < 8; ++mi)
                #pragma unroll
                for (int ni = 0; ni < 4; ++ni)
                    acc[mi][ni] = __builtin_amdgcn_mfma_f32_16x16x32_f16(
                        af[mi], bfr[ni], acc[mi][ni], 0, 0, 0);
        }
    }

    #pragma unroll
    for (int mi = 0; mi < 8; ++mi) {
        #pragma unroll
        for (int ni = 0; ni < 4; ++ni) {
            int col = bn + wn * 64 + ni * 16 + l15;
            int rowb = bm + wm * 128 + mi * 16 + lg * 4;
            f32x4 v = acc[mi][ni];
            float bv = bias[col];
            #pragma unroll
            for (int r = 0; r < 4; ++r)
                C[(size_t)(rowb + r) * DIMM + col] = v[r] + bv;
        }
    }
}

// ---------------------------------------------------------------------------
// Attention core: one block (256 thr) per sample. Fused softmax+PV per thread
// (h,i); k/v in LDS with per-head chunk rotation (conflict-free); q in regs.
// ao written in the GEMM's tiled+swizzled layout (ks == h since DEPTH==64):
//   f16x8 group gk of global row R at vec ((R>>7)*8+h)*1024 + (R&127)*8 + (gk^(R&7))
// ---------------------------------------------------------------------------
__global__ __launch_bounds__(256, 3) void attn_kernel(
    const f16_t* __restrict__ qh, const f16_t* __restrict__ kh,
    const f16_t* __restrict__ vh,
    const float* __restrict__ rel_k, const float* __restrict__ rel_v,
    const int* __restrict__ jmap,
    float* __restrict__ att_out, f16_t* __restrict__ ao)
{
    const int b = blockIdx.x;
    const int tid = threadIdx.x;
    __shared__ __align__(16) f16_t k_s[NJ * DIMM];
    __shared__ __align__(16) f16_t v_s[NJ * DIMM];
    __shared__ float relk_s[4 * DEPTH];
    __shared__ float relv_s[4 * DEPTH];
    __shared__ int map_s[NJ * NJ];
    __shared__ float ksum_s[NJ * DEPTH];
    __shared__ float t4_s[NJ * 4];

    const size_t base = (size_t)b * (NJ * DIMM);
    const uint4* kg = (const uint4*)(kh + base);
    const uint4* vg = (const uint4*)(vh + base);
    uint4* ks4 = (uint4*)k_s;
    uint4* vs4 = (uint4*)v_s;
    for (int c = tid; c < 2 * NJ * 64; c += 256) {   // 2304 16B chunks
        int t = c / (NJ * 64);
        int e = c - t * (NJ * 64);                   // j*64 + m, m = h*8 + tt
        int m = e & 63;
        int pos = (e & ~63) + (m & 56) + (((m & 7) + (m >> 3)) & 7);
        uint4 val = (t == 0 ? kg : vg)[e];
        (t == 0 ? ks4 : vs4)[pos] = val;
    }
    relk_s[tid & 255] = rel_k[tid & 255];
    relv_s[tid & 255] = rel_v[tid & 255];
    for (int e = tid; e < NJ * NJ; e += 256) map_s[e] = jmap[e];

    const int h = tid / NJ, i = tid - (tid / NJ) * NJ;
    const bool act = tid < HEADS * NJ;
    f16x8 qr[8];
    if (act) {
        const f16x8* qp = (const f16x8*)(qh + base + i * DIMM + h * DEPTH);
        #pragma unroll
        for (int t = 0; t < 8; ++t) qr[t] = qp[t];
    }
    __syncthreads();

    const f16x8* ks8 = (const f16x8*)k_s;
    const f16x8* vs8 = (const f16x8*)v_s;

    for (int e = tid; e < NJ * DEPTH; e += 256) {    // ksum[i][d] = sum_h k
        int ii = e >> 6, dd = e & 63;
        int tt = dd >> 3, d7 = dd & 7;
        float s = 0.f;
        #pragma unroll
        for (int hh = 0; hh < HEADS; ++hh)
            s += (float)k_s[((ii << 6) + (hh << 3) + ((tt + hh) & 7)) * 8 + d7];
        ksum_s[e] = s;
    }
    __syncthreads();
    if (tid < NJ * 4) {
        int ii = tid >> 2, c = tid & 3;
        float s = 0.f;
        #pragma unroll
        for (int dd = 0; dd < DEPTH; ++dd)
            s += ksum_s[ii * DEPTH + dd] * relk_s[c * DEPTH + dd];
        t4_s[tid] = s;
    }
    __syncthreads();

    if (!act) return;

    // ---- QK^T + rel bias + softmax (att in registers) ----
    float att[NJ];
    float m = -1e30f;
    #pragma unroll
    for (int j = 0; j < NJ; ++j) {
        float s = 0.f;
        #pragma unroll
        for (int t = 0; t < 8; ++t) {
            f16x8 kv = ks8[(j << 6) + (h << 3) + ((t + h) & 7)];
            f16x8 a = qr[t];
            #pragma unroll
            for (int e = 0; e < 8; ++e) s += (float)a[e] * (float)kv[e];
        }
        s += t4_s[i * 4 + map_s[i * NJ + j]];
        s *= 0.125f;
        att[j] = s;
        m = fmaxf(m, s);
    }
    float sum = 0.f;
    #pragma unroll
    for (int j = 0; j < NJ; ++j) { att[j] = __expf(att[j] - m); sum += att[j]; }
    const float inv = 1.f / sum;
    float s4[4] = {0.f, 0.f, 0.f, 0.f};
    float* ap = att_out + (((size_t)b * HEADS + h) * NJ + i) * NJ;
    #pragma unroll
    for (int j = 0; j < NJ; ++j) {
        float a = att[j] * inv;
        att[j] = a;
        ap[j] = a;
        int c = map_s[i * NJ + j];
        s4[0] += (c == 0) ? a : 0.f;
        s4[1] += (c == 1) ? a : 0.f;
        s4[2] += (c == 2) ? a : 0.f;
        s4[3] += (c == 3) ? a : 0.f;
    }

    // ---- fused PV + rel_v; write ao in tiled+swizzled GEMM-A layout ----
    const size_t grow = (size_t)b * NJ + i;
    f16x8* aot = (f16x8*)ao + ((grow >> 7) * 8 + h) * 1024 + (grow & 127) * 8;
    const int rr7 = (int)(grow & 7);
    #pragma unroll
    for (int half = 0; half < 2; ++half) {
        float acc[32] = {};
        #pragma unroll
        for (int j = 0; j < NJ; ++j) {
            float a = att[j];
            #pragma unroll
            for (int t = 0; t < 4; ++t) {
                int tt = half * 4 + t;
                f16x8 vv = vs8[(j << 6) + (h << 3) + ((tt + h) & 7)];
                #pragma unroll
                for (int e = 0; e < 8; ++e) acc[t * 8 + e] += a * (float)vv[e];
            }
        }
        #pragma unroll
        for (int c = 0; c < 4; ++c) {
            float sc = s4[c];
            #pragma unroll
            for (int d = 0; d < 32; ++d)
                acc[d] += sc * relv_s[c * DEPTH + half * 32 + d];
        }
        #pragma unroll
        for (int t = 0; t < 4; ++t) {
            f16x8 res;
            #pragma unroll
            for (int e = 0; e < 8; ++e) res[e] = (f16_t)acc[t * 8 + e];
            aot[(half * 4 + t) ^ rr7] = res;
        }
    }
}

// ---------------------------------------------------------------------------
extern "C" void kernel_launch(void* const* d_in, const int* in_sizes, int n_in,
                              void* d_out, int out_size, void* d_ws, size_t ws_size,
                              hipStream_t stream) {
    (void)in_sizes; (void)n_in; (void)out_size; (void)ws_size;
    const float* k_in = (const float*)d_in[0];
    const float* v_in = (const float*)d_in[1];
    const float* q_in = (const float*)d_in[2];
    const float* Wq   = (const float*)d_in[3];
    const float* Wk   = (const float*)d_in[4];
    const float* Wv   = (const float*)d_in[5];
    const float* Wo   = (const float*)d_in[6];
    const float* bo   = (const float*)d_in[7];
    const float* relk = (const float*)d_in[8];
    const float* relv = (const float*)d_in[9];
    const int*   jmap = (const int*)d_in[10];

    char* ws = (char*)d_ws;
    const size_t WT = (size_t)DIMM * DIMM * sizeof(f16_t);    // 512 KB each
    f16_t* Tq = (f16_t*)(ws + 0 * WT);
    f16_t* Tk = (f16_t*)(ws + 1 * WT);
    f16_t* Tv = (f16_t*)(ws + 2 * WT);
    f16_t* To = (f16_t*)(ws + 3 * WT);
    const size_t PSZ = (size_t)MROWS * DIMM * sizeof(f16_t);  // 75.5 MB each
    f16_t* qh = (f16_t*)(ws + 4 * WT + 0 * PSZ);
    f16_t* kh = (f16_t*)(ws + 4 * WT + 1 * PSZ);
    f16_t* vh = (f16_t*)(ws + 4 * WT + 2 * PSZ);
    f16_t* ao = (f16_t*)(ws + 4 * WT + 3 * PSZ);  // tiled+swizzled layout

    float* outp = (float*)d_out;
    float* attp = outp + ATT_OFF;

    convert_w_kernel<<<dim3(8, 8, 4), 256, 0, stream>>>(
        Wq, Wk, Wv, Wo, Tq, Tk, Tv, To);

    gemm_qkv_kernel<<<dim3(2, MROWS / 256, 3), 512, 0, stream>>>(
        q_in, k_in, v_in, Tq, Tk, Tv, qh, kh, vh);

    attn_kernel<<<BATCH, 256, 0, stream>>>(qh, kh, vh, relk, relv, jmap, attp, ao);

    gemm_out_kernel<<<dim3(2, MROWS / 256), 512, 0, stream>>>(
        ao, To, outp, bo);
}

// Round 14
// 429.973 us; speedup vs baseline: 1.1102x; 1.1102x over previous
//
#include <hip/hip_runtime.h>
#include <stdint.h>

#define BATCH 4096
#define NJ 18
#define DIMM 512
#define HEADS 8
#define DEPTH 64
#define MROWS (BATCH*NJ)               // 73728
#define ATT_OFF ((size_t)MROWS*DIMM)   // start of att in d_out (floats)

typedef float f32x4 __attribute__((ext_vector_type(4)));
typedef _Float16 f16_t;
typedef _Float16 f16x8 __attribute__((ext_vector_type(8)));

// global -> LDS direct copy, 16 B per lane. LDS dest is wave-uniform base
// + lane*16 (linear); global src is per-lane.
__device__ __forceinline__ void gl_lds16(const unsigned int* g, unsigned int* l) {
    __builtin_amdgcn_global_load_lds(g, l, 16, 0, 0);
}

// ---------------------------------------------------------------------------
// Kernel 0: W[k][n] (f32) -> tiled+swizzled f16 image T.
// Tile (nb, ks) = rows nb*128..+127, k ks*64..+63, one contiguous 16 KB chunk:
//   f16x8 group gk of row rr at vec (nb*8+ks)*1024 + rr*8 + (gk ^ (rr&7))
// ---------------------------------------------------------------------------
__global__ __launch_bounds__(256) void convert_w_kernel(
    const float* __restrict__ W0, const float* __restrict__ W1,
    const float* __restrict__ W2, const float* __restrict__ W3,
    f16_t* __restrict__ T0, f16_t* __restrict__ T1,
    f16_t* __restrict__ T2, f16_t* __restrict__ T3)
{
    const float* W = blockIdx.z == 0 ? W0 : blockIdx.z == 1 ? W1 : blockIdx.z == 2 ? W2 : W3;
    f16_t* T       = blockIdx.z == 0 ? T0 : blockIdx.z == 1 ? T1 : blockIdx.z == 2 ? T2 : T3;
    __shared__ float ld[64][65];
    int k0 = blockIdx.y * 64, n0 = blockIdx.x * 64;
    int tid = threadIdx.x;
    #pragma unroll
    for (int it = 0; it < 16; ++it) {
        int idx = tid + it * 256;
        int kk = idx >> 6, nn = idx & 63;
        ld[kk][nn] = W[(size_t)(k0 + kk) * DIMM + n0 + nn];
    }
    __syncthreads();
    f16x8* T8 = (f16x8*)T;
    #pragma unroll
    for (int it = 0; it < 2; ++it) {
        int c = tid + it * 256;            // 512 f16x8 chunks per 64x64 tile
        int nn = c >> 3, c8 = c & 7;
        int n = n0 + nn, k = k0 + c8 * 8;
        f16x8 val;
        #pragma unroll
        for (int e = 0; e < 8; ++e) val[e] = (f16_t)ld[c8 * 8 + e][nn];
        size_t vi = (size_t)((n >> 7) * 8 + (k >> 6)) * 1024
                  + (n & 127) * 8 + (((k >> 3) & 7) ^ (n & 7));
        T8[vi] = val;
    }
}

// ---------------------------------------------------------------------------
// qkv GEMM (round-12 proven optimum): C = A @ W. 128(M)x256(N) tile, BK=64,
// 512 thr = 8 waves (2x4), per-wave 64x64 via 4x4x2 mfma_f32_16x16x32_f16.
// A f32 reg-staged + cvt into XOR-swizzled As (16 KB); B = two pre-swizzled
// 16 KB images via gl_lds (32 KB). LDS 48 KB -> 3 blocks/CU.
// XCD-aware bijective block swizzle (1152 blocks/slice, %8==0).
// ---------------------------------------------------------------------------
__global__ __launch_bounds__(512) void gemm_qkv_kernel(
    const float* __restrict__ A0, const float* __restrict__ A1,
    const float* __restrict__ A2,
    const f16_t* __restrict__ B0, const f16_t* __restrict__ B1,
    const f16_t* __restrict__ B2,
    f16_t* __restrict__ C0, f16_t* __restrict__ C1, f16_t* __restrict__ C2)
{
    const float* A  = blockIdx.z == 0 ? A0 : blockIdx.z == 1 ? A1 : A2;
    const f16_t* Bt = blockIdx.z == 0 ? B0 : blockIdx.z == 1 ? B1 : B2;
    f16_t* C        = blockIdx.z == 0 ? C0 : blockIdx.z == 1 ? C1 : C2;

    const int p = blockIdx.x + 2 * blockIdx.y;            // nwg = 1152
    const int logical = (p & 7) * (1152 / 8) + (p >> 3);
    const int bn = (logical & 1) * 256;
    const int bm = (logical >> 1) * 128;

    __shared__ __align__(16) f16_t As[128 * 64];          // 16 KB, XOR-swizzled
    __shared__ __align__(16) f16_t Bs[2 * 128 * 64];      // 32 KB, 2 images

    const int tid = threadIdx.x;
    const int lane = tid & 63;
    const int wv = tid >> 6;                              // 0..7
    const int wm = wv >> 2, wn = wv & 3;                  // 2 x 4 wave grid
    const int l15 = lane & 15, lg = lane >> 4;
    const int swz = (l15 & 7) << 4;                       // byte XOR for reads
    const int koffb[2] = { (lg * 16) ^ swz, (lg * 16 + 64) ^ swz };

    f32x4 acc[4][4] = {};

    for (int ks = 0; ks < 8; ++ks) {
        __syncthreads();
        {   // B: two 16 KB tiles (nb0, nb0+1) via gl_lds, 32 chunks of 1 KB
            const unsigned int* bt0 =
                (const unsigned int*)(Bt + (size_t)(((bn >> 7) + 0) * 8 + ks) * 8192);
            const unsigned int* bt1 =
                (const unsigned int*)(Bt + (size_t)(((bn >> 7) + 1) * 8 + ks) * 8192);
            unsigned int* bs = (unsigned int*)Bs;
            #pragma unroll
            for (int it = 0; it < 4; ++it) {
                int chunk = wv * 4 + it;                  // 0..31, wave-uniform half
                const unsigned int* src =
                    (chunk < 16 ? bt0 : bt1) + (chunk & 15) * 256 + lane * 4;
                gl_lds16(src, bs + chunk * 256);
            }
        }
        {   // A: 128x64 f32 reg-stage + cvt; swizzled ds_write
            #pragma unroll
            for (int r = 0; r < 2; ++r) {
                int c = tid + r * 512;                    // 1024 chunks of 8 f32
                int row = c >> 3, kc = c & 7;
                const f32x4* p4 = (const f32x4*)(A + (size_t)(bm + row) * DIMM + ks * 64 + kc * 8);
                f32x4 a0 = p4[0], a1 = p4[1];
                f16x8 val;
                val[0] = (f16_t)a0[0]; val[1] = (f16_t)a0[1];
                val[2] = (f16_t)a0[2]; val[3] = (f16_t)a0[3];
                val[4] = (f16_t)a1[0]; val[5] = (f16_t)a1[1];
                val[6] = (f16_t)a1[2]; val[7] = (f16_t)a1[3];
                ((f16x8*)As)[row * 8 + (kc ^ (row & 7))] = val;
            }
        }
        __syncthreads();

        #pragma unroll
        for (int kk = 0; kk < 2; ++kk) {
            const int koff = koffb[kk];
            f16x8 af[4], bfr[4];
            #pragma unroll
            for (int mi = 0; mi < 4; ++mi) {
                int row = wm * 64 + mi * 16 + l15;        // 0..127
                af[mi] = *(const f16x8*)((const char*)As + row * 128 + koff);
            }
            #pragma unroll
            for (int ni = 0; ni < 4; ++ni) {
                int rn = wn * 64 + ni * 16 + l15;         // 0..255
                bfr[ni] = *(const f16x8*)((const char*)Bs
                            + (rn >> 7) * 16384 + (rn & 127) * 128 + koff);
            }
            #pragma unroll
            for (int mi = 0; mi < 4; ++mi)
                #pragma unroll
                for (int ni = 0; ni < 4; ++ni)
                    acc[mi][ni] = __builtin_amdgcn_mfma_f32_16x16x32_f16(
                        af[mi], bfr[ni], acc[mi][ni], 0, 0, 0);
        }
    }

    // epilogue: C/D layout col = lane&15, row = (lane>>4)*4 + reg  [HW-verified]
    #pragma unroll
    for (int mi = 0; mi < 4; ++mi) {
        #pragma unroll
        for (int ni = 0; ni < 4; ++ni) {
            int col = bn + wn * 64 + ni * 16 + l15;
            int rowb = bm + wm * 64 + mi * 16 + lg * 4;
            f32x4 v = acc[mi][ni];
            #pragma unroll
            for (int r = 0; r < 4; ++r)
                C[(size_t)(rowb + r) * DIMM + col] = (f16_t)v[r];
        }
    }
}

// ---------------------------------------------------------------------------
// Final GEMM: out = ao @ Wo + bo. SAME geometry as qkv (128x256, 512 thr,
// 48 KB): A via ONE gl_lds image (ao pre-tiled), B via two images. f32 C+bias.
// ---------------------------------------------------------------------------
__global__ __launch_bounds__(512) void gemm_out_kernel(
    const f16_t* __restrict__ Aimg, const f16_t* __restrict__ Bt,
    float* __restrict__ C, const float* __restrict__ bias)
{
    const int p = blockIdx.x + 2 * blockIdx.y;            // nwg = 1152
    const int logical = (p & 7) * (1152 / 8) + (p >> 3);
    const int bn = (logical & 1) * 256;
    const int bm = (logical >> 1) * 128;

    __shared__ __align__(16) f16_t As[128 * 64];          // 16 KB
    __shared__ __align__(16) f16_t Bs[2 * 128 * 64];      // 32 KB

    const int tid = threadIdx.x;
    const int lane = tid & 63;
    const int wv = tid >> 6;
    const int wm = wv >> 2, wn = wv & 3;                  // 2 x 4 wave grid
    const int l15 = lane & 15, lg = lane >> 4;
    const int swz = (l15 & 7) << 4;
    const int koffb[2] = { (lg * 16) ^ swz, (lg * 16 + 64) ^ swz };

    f32x4 acc[4][4] = {};

    for (int ks = 0; ks < 8; ++ks) {
        __syncthreads();
        {   // B: two 16 KB tiles via gl_lds
            const unsigned int* bt0 =
                (const unsigned int*)(Bt + (size_t)(((bn >> 7) + 0) * 8 + ks) * 8192);
            const unsigned int* bt1 =
                (const unsigned int*)(Bt + (size_t)(((bn >> 7) + 1) * 8 + ks) * 8192);
            unsigned int* bs = (unsigned int*)Bs;
            #pragma unroll
            for (int it = 0; it < 4; ++it) {
                int chunk = wv * 4 + it;
                const unsigned int* src =
                    (chunk < 16 ? bt0 : bt1) + (chunk & 15) * 256 + lane * 4;
                gl_lds16(src, bs + chunk * 256);
            }
        }
        {   // A: one 16 KB tile via gl_lds (16 chunks, 2 per wave)
            const unsigned int* atile =
                (const unsigned int*)(Aimg + (size_t)((bm >> 7) * 8 + ks) * 8192);
            unsigned int* as = (unsigned int*)As;
            #pragma unroll
            for (int it = 0; it < 2; ++it) {
                int chunk = wv * 2 + it;                  // 0..15
                gl_lds16(atile + chunk * 256 + lane * 4, as + chunk * 256);
            }
        }
        __syncthreads();

        #pragma unroll
        for (int kk = 0; kk < 2; ++kk) {
            const int koff = koffb[kk];
            f16x8 af[4], bfr[4];
            #pragma unroll
            for (int mi = 0; mi < 4; ++mi) {
                int row = wm * 64 + mi * 16 + l15;        // 0..127
                af[mi] = *(const f16x8*)((const char*)As + row * 128 + koff);
            }
            #pragma unroll
            for (int ni = 0; ni < 4; ++ni) {
                int rn = wn * 64 + ni * 16 + l15;         // 0..255
                bfr[ni] = *(const f16x8*)((const char*)Bs
                            + (rn >> 7) * 16384 + (rn & 127) * 128 + koff);
            }
            #pragma unroll
            for (int mi = 0; mi < 4; ++mi)
                #pragma unroll
                for (int ni = 0; ni < 4; ++ni)
                    acc[mi][ni] = __builtin_amdgcn_mfma_f32_16x16x32_f16(
                        af[mi], bfr[ni], acc[mi][ni], 0, 0, 0);
        }
    }

    #pragma unroll
    for (int mi = 0; mi < 4; ++mi) {
        #pragma unroll
        for (int ni = 0; ni < 4; ++ni) {
            int col = bn + wn * 64 + ni * 16 + l15;
            int rowb = bm + wm * 64 + mi * 16 + lg * 4;
            f32x4 v = acc[mi][ni];
            float bv = bias[col];
            #pragma unroll
            for (int r = 0; r < 4; ++r)
                C[(size_t)(rowb + r) * DIMM + col] = v[r] + bv;
        }
    }
}

// ---------------------------------------------------------------------------
// Attention core: one block (256 thr) per sample. Fused softmax+PV per thread
// (h,i); k/v in LDS with per-head chunk rotation (conflict-free); q in regs.
// ao written in the GEMM's tiled+swizzled layout (ks == h since DEPTH==64):
//   f16x8 group gk of global row R at vec ((R>>7)*8+h)*1024 + (R&127)*8 + (gk^(R&7))
// ---------------------------------------------------------------------------
__global__ __launch_bounds__(256, 3) void attn_kernel(
    const f16_t* __restrict__ qh, const f16_t* __restrict__ kh,
    const f16_t* __restrict__ vh,
    const float* __restrict__ rel_k, const float* __restrict__ rel_v,
    const int* __restrict__ jmap,
    float* __restrict__ att_out, f16_t* __restrict__ ao)
{
    const int b = blockIdx.x;
    const int tid = threadIdx.x;
    __shared__ __align__(16) f16_t k_s[NJ * DIMM];
    __shared__ __align__(16) f16_t v_s[NJ * DIMM];
    __shared__ float relk_s[4 * DEPTH];
    __shared__ float relv_s[4 * DEPTH];
    __shared__ int map_s[NJ * NJ];
    __shared__ float ksum_s[NJ * DEPTH];
    __shared__ float t4_s[NJ * 4];

    const size_t base = (size_t)b * (NJ * DIMM);
    const uint4* kg = (const uint4*)(kh + base);
    const uint4* vg = (const uint4*)(vh + base);
    uint4* ks4 = (uint4*)k_s;
    uint4* vs4 = (uint4*)v_s;
    for (int c = tid; c < 2 * NJ * 64; c += 256) {   // 2304 16B chunks
        int t = c / (NJ * 64);
        int e = c - t * (NJ * 64);                   // j*64 + m, m = h*8 + tt
        int m = e & 63;
        int pos = (e & ~63) + (m & 56) + (((m & 7) + (m >> 3)) & 7);
        uint4 val = (t == 0 ? kg : vg)[e];
        (t == 0 ? ks4 : vs4)[pos] = val;
    }
    relk_s[tid & 255] = rel_k[tid & 255];
    relv_s[tid & 255] = rel_v[tid & 255];
    for (int e = tid; e < NJ * NJ; e += 256) map_s[e] = jmap[e];

    const int h = tid / NJ, i = tid - (tid / NJ) * NJ;
    const bool act = tid < HEADS * NJ;
    f16x8 qr[8];
    if (act) {
        const f16x8* qp = (const f16x8*)(qh + base + i * DIMM + h * DEPTH);
        #pragma unroll
        for (int t = 0; t < 8; ++t) qr[t] = qp[t];
    }
    __syncthreads();

    const f16x8* ks8 = (const f16x8*)k_s;
    const f16x8* vs8 = (const f16x8*)v_s;

    for (int e = tid; e < NJ * DEPTH; e += 256) {    // ksum[i][d] = sum_h k
        int ii = e >> 6, dd = e & 63;
        int tt = dd >> 3, d7 = dd & 7;
        float s = 0.f;
        #pragma unroll
        for (int hh = 0; hh < HEADS; ++hh)
            s += (float)k_s[((ii << 6) + (hh << 3) + ((tt + hh) & 7)) * 8 + d7];
        ksum_s[e] = s;
    }
    __syncthreads();
    if (tid < NJ * 4) {
        int ii = tid >> 2, c = tid & 3;
        float s = 0.f;
        #pragma unroll
        for (int dd = 0; dd < DEPTH; ++dd)
            s += ksum_s[ii * DEPTH + dd] * relk_s[c * DEPTH + dd];
        t4_s[tid] = s;
    }
    __syncthreads();

    if (!act) return;

    // ---- QK^T + rel bias + softmax (att in registers) ----
    float att[NJ];
    float m = -1e30f;
    #pragma unroll
    for (int j = 0; j < NJ; ++j) {
        float s = 0.f;
        #pragma unroll
        for (int t = 0; t < 8; ++t) {
            f16x8 kv = ks8[(j << 6) + (h << 3) + ((t + h) & 7)];
            f16x8 a = qr[t];
            #pragma unroll
            for (int e = 0; e < 8; ++e) s += (float)a[e] * (float)kv[e];
        }
        s += t4_s[i * 4 + map_s[i * NJ + j]];
        s *= 0.125f;
        att[j] = s;
        m = fmaxf(m, s);
    }
    float sum = 0.f;
    #pragma unroll
    for (int j = 0; j < NJ; ++j) { att[j] = __expf(att[j] - m); sum += att[j]; }
    const float inv = 1.f / sum;
    float s4[4] = {0.f, 0.f, 0.f, 0.f};
    float* ap = att_out + (((size_t)b * HEADS + h) * NJ + i) * NJ;
    #pragma unroll
    for (int j = 0; j < NJ; ++j) {
        float a = att[j] * inv;
        att[j] = a;
        ap[j] = a;
        int c = map_s[i * NJ + j];
        s4[0] += (c == 0) ? a : 0.f;
        s4[1] += (c == 1) ? a : 0.f;
        s4[2] += (c == 2) ? a : 0.f;
        s4[3] += (c == 3) ? a : 0.f;
    }

    // ---- fused PV + rel_v; write ao in tiled+swizzled GEMM-A layout ----
    const size_t grow = (size_t)b * NJ + i;
    f16x8* aot = (f16x8*)ao + ((grow >> 7) * 8 + h) * 1024 + (grow & 127) * 8;
    const int rr7 = (int)(grow & 7);
    #pragma unroll
    for (int half = 0; half < 2; ++half) {
        float acc[32] = {};
        #pragma unroll
        for (int j = 0; j < NJ; ++j) {
            float a = att[j];
            #pragma unroll
            for (int t = 0; t < 4; ++t) {
                int tt = half * 4 + t;
                f16x8 vv = vs8[(j << 6) + (h << 3) + ((tt + h) & 7)];
                #pragma unroll
                for (int e = 0; e < 8; ++e) acc[t * 8 + e] += a * (float)vv[e];
            }
        }
        #pragma unroll
        for (int c = 0; c < 4; ++c) {
            float sc = s4[c];
            #pragma unroll
            for (int d = 0; d < 32; ++d)
                acc[d] += sc * relv_s[c * DEPTH + half * 32 + d];
        }
        #pragma unroll
        for (int t = 0; t < 4; ++t) {
            f16x8 res;
            #pragma unroll
            for (int e = 0; e < 8; ++e) res[e] = (f16_t)acc[t * 8 + e];
            aot[(half * 4 + t) ^ rr7] = res;
        }
    }
}

// ---------------------------------------------------------------------------
extern "C" void kernel_launch(void* const* d_in, const int* in_sizes, int n_in,
                              void* d_out, int out_size, void* d_ws, size_t ws_size,
                              hipStream_t stream) {
    (void)in_sizes; (void)n_in; (void)out_size; (void)ws_size;
    const float* k_in = (const float*)d_in[0];
    const float* v_in = (const float*)d_in[1];
    const float* q_in = (const float*)d_in[2];
    const float* Wq   = (const float*)d_in[3];
    const float* Wk   = (const float*)d_in[4];
    const float* Wv   = (const float*)d_in[5];
    const float* Wo   = (const float*)d_in[6];
    const float* bo   = (const float*)d_in[7];
    const float* relk = (const float*)d_in[8];
    const float* relv = (const float*)d_in[9];
    const int*   jmap = (const int*)d_in[10];

    char* ws = (char*)d_ws;
    const size_t WT = (size_t)DIMM * DIMM * sizeof(f16_t);    // 512 KB each
    f16_t* Tq = (f16_t*)(ws + 0 * WT);
    f16_t* Tk = (f16_t*)(ws + 1 * WT);
    f16_t* Tv = (f16_t*)(ws + 2 * WT);
    f16_t* To = (f16_t*)(ws + 3 * WT);
    const size_t PSZ = (size_t)MROWS * DIMM * sizeof(f16_t);  // 75.5 MB each
    f16_t* qh = (f16_t*)(ws + 4 * WT + 0 * PSZ);
    f16_t* kh = (f16_t*)(ws + 4 * WT + 1 * PSZ);
    f16_t* vh = (f16_t*)(ws + 4 * WT + 2 * PSZ);
    f16_t* ao = (f16_t*)(ws + 4 * WT + 3 * PSZ);  // tiled+swizzled layout

    float* outp = (float*)d_out;
    float* attp = outp + ATT_OFF;

    convert_w_kernel<<<dim3(8, 8, 4), 256, 0, stream>>>(
        Wq, Wk, Wv, Wo, Tq, Tk, Tv, To);

    gemm_qkv_kernel<<<dim3(2, MROWS / 128, 3), 512, 0, stream>>>(
        q_in, k_in, v_in, Tq, Tk, Tv, qh, kh, vh);

    attn_kernel<<<BATCH, 256, 0, stream>>>(qh, kh, vh, relk, relv, jmap, attp, ao);

    gemm_out_kernel<<<dim3(2, MROWS / 128), 512, 0, stream>>>(
        ao, To, outp, bo);
}